// Round 1
// baseline (141.113 us; speedup 1.0000x reference)
//
#include <hip/hip_runtime.h>

// PhraseAveragePretrainedEmbedding — prefix-sum formulation.
// out[b,t,:] = mean over r in span(lo,hi) of W[leaves[b,r],:]
// where spans are contiguous => use per-batch prefix sums over gathered rows.
//
// Pipeline (all on `stream`, stream-ordered):
//   1. leaves_kernel  : stream-compact leaf tokens per batch (ballot scan)
//   2. chunksum_kernel: per-64-row chunk sums of W[leaves] (D-parallel)
//   3. scan_kernel    : exclusive scan of chunk sums along chunks
//   4. prefix_kernel  : write full prefix table P[b, 0..S, d]
//   5. out_kernel     : out = (P[e]-P[a]) / max(e-a,1)

#define BB 8
#define TT 4095
#define SS 2048
#define DD 300
#define PADIDX 1
#define CHUNK 64
#define NC (SS / CHUNK)  // 32

__global__ __launch_bounds__(256) void leaves_kernel(const int* __restrict__ x,
                                                     const int* __restrict__ idx,
                                                     int* __restrict__ leaves) {
    int b = blockIdx.x;
    int tid = threadIdx.x;
    int lane = tid & 63, w = tid >> 6;  // 4 waves of 64
    __shared__ int wcnt[4];
    __shared__ int sbase;
    if (tid == 0) sbase = 0;
    __syncthreads();
    const int* xb = x + b * TT;
    const int* ib = idx + b * 2 * TT;
    for (int t0 = 0; t0 < TT; t0 += 256) {
        int t = t0 + tid;
        bool leaf = false;
        int xv = 0;
        if (t < TT) {
            xv = xb[t];
            int lo = ib[2 * t], hi = ib[2 * t + 1];
            leaf = (lo == hi) && (xv != PADIDX);
        }
        unsigned long long bal = __ballot(leaf);
        if (lane == 0) wcnt[w] = __popcll(bal);
        __syncthreads();
        int off = sbase;
        for (int i = 0; i < w; ++i) off += wcnt[i];
        int pos = off + __popcll(bal & ((1ull << lane) - 1ull));
        if (leaf && pos < SS) leaves[b * SS + pos] = xv;
        __syncthreads();
        if (tid == 0) sbase += wcnt[0] + wcnt[1] + wcnt[2] + wcnt[3];
        __syncthreads();
    }
    int total = sbase;
    for (int i = total + tid; i < SS; i += 256) leaves[b * SS + i] = PADIDX;
}

__global__ __launch_bounds__(320) void chunksum_kernel(const int* __restrict__ leaves,
                                                       const float* __restrict__ W,
                                                       float* __restrict__ csum) {
    int blk = blockIdx.x;
    int b = blk / NC, c = blk - b * NC;
    __shared__ int lf[CHUNK];
    if (threadIdx.x < CHUNK) lf[threadIdx.x] = leaves[b * SS + c * CHUNK + threadIdx.x];
    __syncthreads();
    int d = threadIdx.x;
    if (d >= DD) return;
    float acc = 0.f;
#pragma unroll 8
    for (int i = 0; i < CHUNK; ++i) acc += W[lf[i] * DD + d];
    csum[(b * NC + c) * DD + d] = acc;
}

__global__ __launch_bounds__(320) void scan_kernel(float* __restrict__ csum) {
    int b = blockIdx.x;
    int d = threadIdx.x;
    if (d >= DD) return;
    float run = 0.f;
    for (int c = 0; c < NC; ++c) {
        int o = (b * NC + c) * DD + d;
        float v = csum[o];
        csum[o] = run;
        run += v;
    }
}

__global__ __launch_bounds__(320) void prefix_kernel(const int* __restrict__ leaves,
                                                     const float* __restrict__ W,
                                                     const float* __restrict__ csum,
                                                     float* __restrict__ P) {
    int blk = blockIdx.x;
    int b = blk / NC, c = blk - b * NC;
    __shared__ int lf[CHUNK];
    if (threadIdx.x < CHUNK) lf[threadIdx.x] = leaves[b * SS + c * CHUNK + threadIdx.x];
    __syncthreads();
    int d = threadIdx.x;
    if (d >= DD) return;
    float acc = csum[(b * NC + c) * DD + d];
    float* Pb = P + b * (SS + 1) * DD;
    int s0 = c * CHUNK;
#pragma unroll 4
    for (int i = 0; i < CHUNK; ++i) {
        Pb[(s0 + i) * DD + d] = acc;
        acc += W[lf[i] * DD + d];
    }
    if (c == NC - 1) Pb[SS * DD + d] = acc;
}

__global__ __launch_bounds__(320) void out_kernel(const int* __restrict__ idx,
                                                  const float* __restrict__ P,
                                                  float* __restrict__ out) {
    int bt = blockIdx.x;
    int b = bt / TT;
    int lo = idx[bt * 2], hi = idx[bt * 2 + 1];
    int u = hi + 1;
    int a = min(lo, u), e = max(lo, u);
    a = max(0, min(a, SS));
    e = max(0, min(e, SS));
    int cnt = e - a;
    float inv = 1.0f / (float)(cnt > 0 ? cnt : 1);
    int d = threadIdx.x;
    if (d >= DD) return;
    const float* Pb = P + b * (SS + 1) * DD;
    out[bt * DD + d] = (Pb[e * DD + d] - Pb[a * DD + d]) * inv;
}

extern "C" void kernel_launch(void* const* d_in, const int* in_sizes, int n_in,
                              void* d_out, int out_size, void* d_ws, size_t ws_size,
                              hipStream_t stream) {
    const int* x = (const int*)d_in[0];
    const int* idx = (const int*)d_in[1];
    const float* W = (const float*)d_in[2];
    float* out = (float*)d_out;

    char* ws = (char*)d_ws;
    int* leaves = (int*)ws;                          // B*S ints        = 64 KiB
    float* csum = (float*)(ws + 65536);              // B*NC*D floats   = 300 KiB
    float* P = (float*)(ws + 65536 + 307200);        // B*(S+1)*D float = 18.8 MiB

    leaves_kernel<<<BB, 256, 0, stream>>>(x, idx, leaves);
    chunksum_kernel<<<BB * NC, 320, 0, stream>>>(leaves, W, csum);
    scan_kernel<<<BB, 320, 0, stream>>>(csum);
    prefix_kernel<<<BB * NC, 320, 0, stream>>>(leaves, W, csum, P);
    out_kernel<<<BB * TT, 320, 0, stream>>>(idx, P, out);
}